// Round 7
// baseline (997.928 us; speedup 1.0000x reference)
//
#include <hip/hip_runtime.h>
#include <hip/hip_bf16.h>

#define B_   4
#define H_   16
#define LQ   1024
#define LK   2048
#define D_   1024
#define DH   64

typedef __attribute__((ext_vector_type(8))) short  short8;
typedef __attribute__((ext_vector_type(4))) float  float4_;
typedef __attribute__((ext_vector_type(4))) unsigned int uint4_;

static __device__ __forceinline__ float bf2f(unsigned short u) {
    unsigned int x = ((unsigned int)u) << 16;
    return __builtin_bit_cast(float, x);
}
static __device__ __forceinline__ unsigned short f2bf(float f) {
    unsigned int x = __builtin_bit_cast(unsigned int, f);
    unsigned int lsb = (x >> 16) & 1u;
    x += 0x7fffu + lsb;
    return (unsigned short)(x >> 16);
}
// packed RNE fp32x2 -> bf16x2 (v_cvt_pk_bf16_f32 on gfx950)
static __device__ __forceinline__ unsigned int pack2(float a, float b) {
    __hip_bfloat162 h = __float22bfloat162_rn(make_float2(a, b));
    unsigned int r;
    __builtin_memcpy(&r, &h, 4);
    return r;
}

#define MFMA(a, b, c) __builtin_amdgcn_mfma_f32_16x16x32_bf16((a), (b), (c), 0, 0, 0)

// ---------------------------------------------------------------------------
// One-shot fp32 -> bf16 conversion: Wq, Wk, Wv (1M elems each), dist_emb.
// ---------------------------------------------------------------------------
__global__ __launch_bounds__(256) void conv_kernel(
    const float* __restrict__ Wq, const float* __restrict__ Wk,
    const float* __restrict__ Wv, const float* __restrict__ Eg,
    unsigned short* __restrict__ cWq, unsigned short* __restrict__ cWk,
    unsigned short* __restrict__ cWv, unsigned short* __restrict__ cEb)
{
    int bid = blockIdx.x;
    const float* src; unsigned short* dst; int nch;
    if (bid < 512)       { src = Wq; dst = cWq;              nch = 131072; }
    else if (bid < 1024) { src = Wk; dst = cWk; bid -= 512;  nch = 131072; }
    else if (bid < 1536) { src = Wv; dst = cWv; bid -= 1024; nch = 131072; }
    else                 { src = Eg; dst = cEb; bid -= 1536; nch = 32760;  }
    int ch = bid * 256 + threadIdx.x;
    if (ch >= nch) return;
    const float* s = src + (size_t)ch * 8;
    float4_ v0 = *(const float4_*)s, v1 = *(const float4_*)(s + 4);
    uint4_ o;
    o[0] = pack2(v0[0], v0[1]); o[1] = pack2(v0[2], v0[3]);
    o[2] = pack2(v1[0], v1[1]); o[3] = pack2(v1[2], v1[3]);
    *(uint4_*)(dst + (size_t)ch * 8) = o;
}

// ---------------------------------------------------------------------------
// Projection GEMM: X fp32 (packed in staging), W bf16 (preconverted).
// which 0: Q -> Qh ; 1: K -> Kh ; 2: V -> VT (transposed via LDS).
// ---------------------------------------------------------------------------
__global__ __launch_bounds__(256) void proj_kernel(
    const float* __restrict__ Xq, const float* __restrict__ Xk,
    const unsigned short* __restrict__ Wq, const float* __restrict__ bq,
    const unsigned short* __restrict__ Wk, const float* __restrict__ bk,
    const unsigned short* __restrict__ Wv, const float* __restrict__ bv,
    unsigned short* __restrict__ Qh, unsigned short* __restrict__ Kh,
    unsigned short* __restrict__ VT)
{
    __shared__ short smem[17408];
    short* As = smem;                  // 128 x 40 bf16
    short* Bs = smem + 5120;           // 128 x 40 bf16
    short* Cs = smem;                  // 128 x 136 (V transpose, aliases)

    int bid = blockIdx.x;
    int which, tm, tn;
    const float *X, *bias; const unsigned short* W;
    if (bid < 256)      { which = 0; int t = bid;       tm = t >> 3; tn = t & 7; X = Xq; W = Wq; bias = bq; }
    else if (bid < 768) { which = 1; int t = bid - 256; tm = t >> 3; tn = t & 7; X = Xk; W = Wk; bias = bk; }
    else                { which = 2; int t = bid - 768; tm = t >> 3; tn = t & 7; X = Xk; W = Wv; bias = bv; }

    int tid  = threadIdx.x;
    int wave = tid >> 6, lane = tid & 63;
    int wr = (wave >> 1) * 64, wc = (wave & 1) * 64;
    int m0 = tm * 128, n0 = tn * 128;

    float4_ acc[4][4];
    for (int a = 0; a < 4; ++a) for (int c = 0; c < 4; ++c) acc[a][c] = (float4_)0.0f;

    int srow = tid >> 2, skp = (tid & 3) * 8;
    const float*          Ag = X + (size_t)(m0 + srow) * D_ + skp;
    const unsigned short* Bg = W + (size_t)(n0 + srow) * D_ + skp;
    int lrow = lane & 15, lk8 = (lane >> 4) * 8;

    for (int kt = 0; kt < 32; ++kt) {
        int k0 = kt * 32;
        for (int i = 0; i < 2; ++i) {
            int row = srow + i * 64;
            const float* pa = Ag + (size_t)i * 64 * D_ + k0;
            float4_ a0 = *(const float4_*)(pa);
            float4_ a1 = *(const float4_*)(pa + 4);
            uint4_ va;
            va[0] = pack2(a0[0], a0[1]); va[1] = pack2(a0[2], a0[3]);
            va[2] = pack2(a1[0], a1[1]); va[3] = pack2(a1[2], a1[3]);
            uint4_ vb = *(const uint4_*)(Bg + (size_t)i * 64 * D_ + k0);
            *(uint4_*)(&As[row * 40 + skp]) = va;
            *(uint4_*)(&Bs[row * 40 + skp]) = vb;
        }
        __syncthreads();
        short8 af[4], bfr[4];
        for (int rt = 0; rt < 4; ++rt) af[rt]  = *(const short8*)(&As[(wr + rt * 16 + lrow) * 40 + lk8]);
        for (int ct = 0; ct < 4; ++ct) bfr[ct] = *(const short8*)(&Bs[(wc + ct * 16 + lrow) * 40 + lk8]);
        for (int rt = 0; rt < 4; ++rt)
            for (int ct = 0; ct < 4; ++ct)
                acc[rt][ct] = MFMA(af[rt], bfr[ct], acc[rt][ct]);
        __syncthreads();
    }

    int lrow4 = (lane >> 4) * 4, lcol = lane & 15;
    if (which < 2) {
        int lsh = (which == 0) ? 10 : 11;          // LQ=1024, LK=2048
        int Lm1 = (1 << lsh) - 1;
        unsigned short* dst = (which == 0) ? Qh : Kh;
        for (int rt = 0; rt < 4; ++rt)
            for (int ct = 0; ct < 4; ++ct)
                for (int i = 0; i < 4; ++i) {
                    int m = m0 + wr + rt * 16 + lrow4 + i;
                    int n = n0 + wc + ct * 16 + lcol;
                    float v = acc[rt][ct][i] + bias[n];
                    int b = m >> lsh, s = m & Lm1;
                    int h = n >> 6, d = n & 63;
                    dst[((size_t)((b * H_ + h) << lsh) + (size_t)s) * DH + d] = f2bf(v);
                }
    } else {
        for (int rt = 0; rt < 4; ++rt)
            for (int ct = 0; ct < 4; ++ct)
                for (int i = 0; i < 4; ++i) {
                    int rl = wr + rt * 16 + lrow4 + i;   // tile row (seq)
                    int cl = wc + ct * 16 + lcol;        // tile col (h*64+d)
                    float v = acc[rt][ct][i] + bias[n0 + cl];
                    Cs[cl * 136 + rl] = (short)f2bf(v);
                }
        __syncthreads();
        int b = m0 >> 11, r0 = m0 & 2047;
        int c = tid >> 1, half = tid & 1;
        int n = n0 + c, h = n >> 6, d = n & 63;
        unsigned short* dstp = VT + ((size_t)(b * H_ + h) * DH + d) * LK + r0 + half * 64;
        for (int j = 0; j < 8; ++j) {
            uint4_ v = *(const uint4_*)(&Cs[c * 136 + half * 64 + j * 8]);
            *(uint4_*)(dstp + j * 8) = v;
        }
    }
}

// ---------------------------------------------------------------------------
// Flash attention with relative_key_query pe terms.
// Round-7 changes vs round-6 (logic identical, perf only):
//  * XCD swizzle: all 16 Q-tiles of one (b,h) share bid%8 -> same XCD L2.
//  * Register prefetch of next iter's K/V/E tiles (global latency hidden
//    behind a full iteration of compute; staging ds_writes consume regs).
//  * G2 row stride 144 -> 152 shorts (304 B, 16B-aligned; breaks the
//    mod-128B row aliasing that caused 5e7 bank-conflict cycles).
// ---------------------------------------------------------------------------
__global__ __launch_bounds__(256, 4) void attn_kernel(
    const unsigned short* __restrict__ Qh, const unsigned short* __restrict__ Kh,
    const unsigned short* __restrict__ VT, const unsigned short* __restrict__ Eb,
    const float* __restrict__ mask, float* __restrict__ out)
{
    __shared__ short smem[18944];        // 37888 B
    short* Qs  = smem;                   // 64 x 72 (aliases Ks)
    short* Ks  = smem;                   // 64 x 72
    short* VTs = smem + 4608;            // 64 x 72 (d-major)
    short* Es  = smem + 9216;            // 128 x 72 (aliases G2)
    short* G2  = smem + 9216;            // 64 x 152

    int bid = blockIdx.x;
    // XCD-locality swizzle: xcd = bid&7 (round-robin heuristic), 8 heads/XCD.
    int xcd = bid & 7, grp = (bid >> 3) & 7, tq = bid >> 6;
    int bh = xcd * 8 + grp;
    int l0 = tq * 64;
    int b  = bh >> 4, h = bh & 15;
    int tid = threadIdx.x, wave = tid >> 6, lane = tid & 63;
    int lr = lane & 15, lk8 = (lane >> 4) * 8, lr4 = (lane >> 4) * 4;

    // Stage Q tile, pull frags to registers, then Qs memory is released to Ks.
    for (int i = 0; i < 2; ++i) {
        int idx = tid + 256 * i, row = idx >> 3, g = (idx & 7) * 8;
        *(uint4_*)(&Qs[row * 72 + g]) =
            *(const uint4_*)(Qh + ((size_t)(bh * LQ + l0 + row)) * DH + g);
    }
    __syncthreads();
    short8 aq0 = *(const short8*)(&Qs[(wave * 16 + lr) * 72 + lk8]);
    short8 aq1 = *(const short8*)(&Qs[(wave * 16 + lr) * 72 + 32 + lk8]);

    float m_i[4], l_i[4];
    float4_ Oacc[4];
    for (int i = 0; i < 4; ++i) { m_i[i] = -1e30f; l_i[i] = 0.f; Oacc[i] = (float4_)0.f; }

    const unsigned short* Kbase = Kh + (size_t)bh * LK * DH;
    const unsigned short* Vbase = VT + (size_t)bh * DH * LK;

    int srow = tid >> 3;          // 0..31
    int sg   = (tid & 7) * 8;     // 0..56

    uint4_ kr0, kr1, vr0, vr1, er0, er1, er2, er3;
    auto load_tiles = [&](int it2) {
        int r0_ = it2 * 64, jb_ = l0 - r0_ + 1984;
        kr0 = *(const uint4_*)(Kbase + (size_t)(r0_ + srow) * DH + sg);
        kr1 = *(const uint4_*)(Kbase + (size_t)(r0_ + srow + 32) * DH + sg);
        vr0 = *(const uint4_*)(Vbase + (size_t)srow * LK + r0_ + sg);
        vr1 = *(const uint4_*)(Vbase + (size_t)(srow + 32) * LK + r0_ + sg);
        er0 = *(const uint4_*)(Eb + (size_t)(jb_ + srow) * DH + sg);
        er1 = *(const uint4_*)(Eb + (size_t)(jb_ + srow + 32) * DH + sg);
        er2 = *(const uint4_*)(Eb + (size_t)(jb_ + srow + 64) * DH + sg);
        er3 = *(const uint4_*)(Eb + (size_t)(jb_ + srow + 96) * DH + sg);
    };
    load_tiles(0);

    for (int it = 0; it < 32; ++it) {
        int r0 = it * 64;

        __syncthreads();   // (A) prior-iter readers done -> safe to restage
        *(uint4_*)(&Ks[srow * 72 + sg])         = kr0;
        *(uint4_*)(&Ks[(srow + 32) * 72 + sg])  = kr1;
        *(uint4_*)(&VTs[srow * 72 + sg])        = vr0;
        *(uint4_*)(&VTs[(srow + 32) * 72 + sg]) = vr1;
        *(uint4_*)(&Es[srow * 72 + sg])         = er0;
        *(uint4_*)(&Es[(srow + 32) * 72 + sg])  = er1;
        *(uint4_*)(&Es[(srow + 64) * 72 + sg])  = er2;
        *(uint4_*)(&Es[(srow + 96) * 72 + sg])  = er3;
        __syncthreads();   // (B) staging visible
        if (it < 31) load_tiles(it + 1);   // prefetch next tiles into regs

        // S = Q K^T
        float4_ Sacc[4];
        for (int c = 0; c < 4; ++c) {
            short8 b0 = *(const short8*)(&Ks[(c * 16 + lr) * 72 + lk8]);
            short8 b1 = *(const short8*)(&Ks[(c * 16 + lr) * 72 + 32 + lk8]);
            float4_ s = (float4_)0.f;
            s = MFMA(aq0, b0, s);
            s = MFMA(aq1, b1, s);
            Sacc[c] = s;
        }

        // Gq (u-tiles wave..wave+4), Gk (u-tiles 3-wave..7-wave); pack to bf16.
        short8 ak0 = *(const short8*)(&Ks[(wave * 16 + lr) * 72 + lk8]);
        short8 ak1 = *(const short8*)(&Ks[(wave * 16 + lr) * 72 + 32 + lk8]);
        unsigned int gqp[5][2], gkp[5][2];
        for (int tt = 0; tt < 5; ++tt) {
            int tqi = wave + tt;
            short8 e0 = *(const short8*)(&Es[(tqi * 16 + lr) * 72 + lk8]);
            short8 e1 = *(const short8*)(&Es[(tqi * 16 + lr) * 72 + 32 + lk8]);
            float4_ g = (float4_)0.f;
            g = MFMA(aq0, e0, g); g = MFMA(aq1, e1, g);
            gqp[tt][0] = pack2(g[0], g[1]); gqp[tt][1] = pack2(g[2], g[3]);
            int tk = (3 - wave) + tt;
            short8 f0 = *(const short8*)(&Es[(tk * 16 + lr) * 72 + lk8]);
            short8 f1 = *(const short8*)(&Es[(tk * 16 + lr) * 72 + 32 + lk8]);
            float4_ gg = (float4_)0.f;
            gg = MFMA(ak0, f0, gg); gg = MFMA(ak1, f1, gg);
            gkp[tt][0] = pack2(gg[0], gg[1]); gkp[tt][1] = pack2(gg[2], gg[3]);
        }
        __syncthreads();   // (C) all Es reads done -> scatter may overwrite union

        for (int tt = 0; tt < 5; ++tt) {
            int uq = (wave + tt) * 16 + lr;
            int uk = (3 - wave + tt) * 16 + lr;
            for (int i = 0; i < 4; ++i) {
                int row = wave * 16 + lr4 + i;
                unsigned int wq32 = gqp[tt][i >> 1], wk32 = gkp[tt][i >> 1];
                unsigned short vq = (unsigned short)((i & 1) ? (wq32 >> 16) : (wq32 & 0xffff));
                unsigned short vk = (unsigned short)((i & 1) ? (wk32 >> 16) : (wk32 & 0xffff));
                int tr = row - uq + 63;
                if ((unsigned)tr < 64u)
                    G2[row * 152 + (((tr & 15) ^ (row & 7)) << 3) + ((tr >> 4) << 1)] = (short)vq;
                int tl = uk + row - 63;
                if ((unsigned)tl < 64u)
                    G2[tl * 152 + (((row & 15) ^ (tl & 7)) << 3) + ((row >> 4) << 1) + 1] = (short)vk;
            }
        }
        __syncthreads();   // (D) scatter visible

        // Softmax rows + P write (row tl fully consumed before its P overwrite).
        float mk[4];
        for (int c = 0; c < 4; ++c) mk[c] = mask[b * LK + r0 + c * 16 + lr];
        for (int i = 0; i < 4; ++i) {
            int tl = wave * 16 + lr4 + i;
            short8 gv = *(const short8*)(&G2[tl * 152 + ((lr ^ (tl & 7)) << 3)]);
            float scv[4], mx = -1e30f;
            for (int c = 0; c < 4; ++c) {
                float sq = bf2f((unsigned short)gv[2 * c]);
                float sk = bf2f((unsigned short)gv[2 * c + 1]);
                float sc = (Sacc[c][i] + sq + sk) * 0.125f + mk[c];
                scv[c] = sc;
                mx = fmaxf(mx, sc);
            }
            for (int off = 1; off < 16; off <<= 1) mx = fmaxf(mx, __shfl_xor(mx, off, 64));
            float mnew = fmaxf(m_i[i], mx);
            float alpha = __expf(m_i[i] - mnew);
            m_i[i] = mnew;
            float e0 = __expf(scv[0] - mnew), e1 = __expf(scv[1] - mnew);
            float e2 = __expf(scv[2] - mnew), e3 = __expf(scv[3] - mnew);
            unsigned int p01 = pack2(e0, e1), p23 = pack2(e2, e3);
            float rs = bf2f((unsigned short)(p01 & 0xffff)) + bf2f((unsigned short)(p01 >> 16))
                     + bf2f((unsigned short)(p23 & 0xffff)) + bf2f((unsigned short)(p23 >> 16));
            for (int off = 1; off < 16; off <<= 1) rs += __shfl_xor(rs, off, 64);
            l_i[i] = l_i[i] * alpha + rs;
            for (int nt = 0; nt < 4; ++nt) Oacc[nt][i] *= alpha;
            G2[tl * 152 +  0 + lr] = (short)(unsigned short)(p01 & 0xffff);
            G2[tl * 152 + 16 + lr] = (short)(unsigned short)(p01 >> 16);
            G2[tl * 152 + 32 + lr] = (short)(unsigned short)(p23 & 0xffff);
            G2[tl * 152 + 48 + lr] = (short)(unsigned short)(p23 >> 16);
        }
        // P·V (P A-frags from G2 rows; same-wave in-order LDS => safe)
        short8 ap0 = *(const short8*)(&G2[(wave * 16 + lr) * 152 + lk8]);
        short8 ap1 = *(const short8*)(&G2[(wave * 16 + lr) * 152 + 32 + lk8]);
        for (int nt = 0; nt < 4; ++nt) {
            short8 v0 = *(const short8*)(&VTs[(nt * 16 + lr) * 72 + lk8]);
            short8 v1 = *(const short8*)(&VTs[(nt * 16 + lr) * 72 + 32 + lk8]);
            Oacc[nt] = MFMA(ap0, v0, Oacc[nt]);
            Oacc[nt] = MFMA(ap1, v1, Oacc[nt]);
        }
    }

    // Epilogue: out[b][l][h*64+d] = O / l_i   (fp32 output)
    for (int nt = 0; nt < 4; ++nt)
        for (int i = 0; i < 4; ++i) {
            int row = l0 + wave * 16 + lr4 + i;
            int col = h * 64 + nt * 16 + lr;
            out[(size_t)(b * LQ + row) * D_ + col] = Oacc[nt][i] / l_i[i];
        }
}

extern "C" void kernel_launch(void* const* d_in, const int* in_sizes, int n_in,
                              void* d_out, int out_size, void* d_ws, size_t ws_size,
                              hipStream_t stream) {
    (void)in_sizes; (void)n_in; (void)out_size; (void)ws_size;
    const float* Xk   = (const float*)d_in[0]; // hidden_states [4,2048,1024] fp32
    const float* Xq   = (const float*)d_in[1]; // query_hidden  [4,1024,1024] fp32
    const float* mask = (const float*)d_in[2]; // [4,1,1,2048] fp32
    const float* Wq   = (const float*)d_in[3];
    const float* bq   = (const float*)d_in[4];
    const float* Wk   = (const float*)d_in[5];
    const float* bk   = (const float*)d_in[6];
    const float* Wv   = (const float*)d_in[7];
    const float* bv   = (const float*)d_in[8];
    const float* Eg   = (const float*)d_in[9]; // dist_emb [4095,64] fp32

    // workspace layout (bf16 elems), total ~48.8 MB
    unsigned short* Qh  = (unsigned short*)d_ws;              //  4,194,304
    unsigned short* Kh  = Qh  + (size_t)4194304;              //  8,388,608
    unsigned short* VT  = Kh  + (size_t)8388608;              //  8,388,608
    unsigned short* cWq = VT  + (size_t)8388608;              //  1,048,576
    unsigned short* cWk = cWq + (size_t)1048576;              //  1,048,576
    unsigned short* cWv = cWk + (size_t)1048576;              //  1,048,576
    unsigned short* cEb = cWv + (size_t)1048576;              //    262,144 (pad)
    float* o = (float*)d_out;

    conv_kernel<<<1664, 256, 0, stream>>>(Wq, Wk, Wv, Eg, cWq, cWk, cWv, cEb);
    proj_kernel<<<1280, 256, 0, stream>>>(Xq, Xk, cWq, bq, cWk, bk, cWv, bv, Qh, Kh, VT);
    attn_kernel<<<1024, 256, 0, stream>>>(Qh, Kh, VT, cEb, mask, o);
}

// Round 8
// 535.237 us; speedup vs baseline: 1.8645x; 1.8645x over previous
//
#include <hip/hip_runtime.h>
#include <hip/hip_bf16.h>

#define B_   4
#define H_   16
#define LQ   1024
#define LK   2048
#define D_   1024
#define DH   64

typedef __attribute__((ext_vector_type(8))) short  short8;
typedef __attribute__((ext_vector_type(4))) float  float4_;
typedef __attribute__((ext_vector_type(4))) unsigned int uint4_;

static __device__ __forceinline__ float bf2f(unsigned short u) {
    unsigned int x = ((unsigned int)u) << 16;
    return __builtin_bit_cast(float, x);
}
static __device__ __forceinline__ unsigned short f2bf(float f) {
    unsigned int x = __builtin_bit_cast(unsigned int, f);
    unsigned int lsb = (x >> 16) & 1u;
    x += 0x7fffu + lsb;
    return (unsigned short)(x >> 16);
}
// packed RNE fp32x2 -> bf16x2 (v_cvt_pk_bf16_f32 on gfx950)
static __device__ __forceinline__ unsigned int pack2(float a, float b) {
    __hip_bfloat162 h = __float22bfloat162_rn(make_float2(a, b));
    unsigned int r;
    __builtin_memcpy(&r, &h, 4);
    return r;
}

#define MFMA(a, b, c) __builtin_amdgcn_mfma_f32_16x16x32_bf16((a), (b), (c), 0, 0, 0)

// ---------------------------------------------------------------------------
// One-shot fp32 -> bf16 conversion: Wq, Wk, Wv (1M elems each), dist_emb.
// ---------------------------------------------------------------------------
__global__ __launch_bounds__(256) void conv_kernel(
    const float* __restrict__ Wq, const float* __restrict__ Wk,
    const float* __restrict__ Wv, const float* __restrict__ Eg,
    unsigned short* __restrict__ cWq, unsigned short* __restrict__ cWk,
    unsigned short* __restrict__ cWv, unsigned short* __restrict__ cEb)
{
    int bid = blockIdx.x;
    const float* src; unsigned short* dst; int nch;
    if (bid < 512)       { src = Wq; dst = cWq;              nch = 131072; }
    else if (bid < 1024) { src = Wk; dst = cWk; bid -= 512;  nch = 131072; }
    else if (bid < 1536) { src = Wv; dst = cWv; bid -= 1024; nch = 131072; }
    else                 { src = Eg; dst = cEb; bid -= 1536; nch = 32760;  }
    int ch = bid * 256 + threadIdx.x;
    if (ch >= nch) return;
    const float* s = src + (size_t)ch * 8;
    float4_ v0 = *(const float4_*)s, v1 = *(const float4_*)(s + 4);
    uint4_ o;
    o[0] = pack2(v0[0], v0[1]); o[1] = pack2(v0[2], v0[3]);
    o[2] = pack2(v1[0], v1[1]); o[3] = pack2(v1[2], v1[3]);
    *(uint4_*)(dst + (size_t)ch * 8) = o;
}

// ---------------------------------------------------------------------------
// Projection GEMM: X fp32 (packed in staging), W bf16 (preconverted).
// which 0: Q -> Qh ; 1: K -> Kh ; 2: V -> VT (transposed via LDS).
// ---------------------------------------------------------------------------
__global__ __launch_bounds__(256) void proj_kernel(
    const float* __restrict__ Xq, const float* __restrict__ Xk,
    const unsigned short* __restrict__ Wq, const float* __restrict__ bq,
    const unsigned short* __restrict__ Wk, const float* __restrict__ bk,
    const unsigned short* __restrict__ Wv, const float* __restrict__ bv,
    unsigned short* __restrict__ Qh, unsigned short* __restrict__ Kh,
    unsigned short* __restrict__ VT)
{
    __shared__ short smem[17408];
    short* As = smem;                  // 128 x 40 bf16
    short* Bs = smem + 5120;           // 128 x 40 bf16
    short* Cs = smem;                  // 128 x 136 (V transpose, aliases)

    int bid = blockIdx.x;
    int which, tm, tn;
    const float *X, *bias; const unsigned short* W;
    if (bid < 256)      { which = 0; int t = bid;       tm = t >> 3; tn = t & 7; X = Xq; W = Wq; bias = bq; }
    else if (bid < 768) { which = 1; int t = bid - 256; tm = t >> 3; tn = t & 7; X = Xk; W = Wk; bias = bk; }
    else                { which = 2; int t = bid - 768; tm = t >> 3; tn = t & 7; X = Xk; W = Wv; bias = bv; }

    int tid  = threadIdx.x;
    int wave = tid >> 6, lane = tid & 63;
    int wr = (wave >> 1) * 64, wc = (wave & 1) * 64;
    int m0 = tm * 128, n0 = tn * 128;

    float4_ acc[4][4];
    for (int a = 0; a < 4; ++a) for (int c = 0; c < 4; ++c) acc[a][c] = (float4_)0.0f;

    int srow = tid >> 2, skp = (tid & 3) * 8;
    const float*          Ag = X + (size_t)(m0 + srow) * D_ + skp;
    const unsigned short* Bg = W + (size_t)(n0 + srow) * D_ + skp;
    int lrow = lane & 15, lk8 = (lane >> 4) * 8;

    for (int kt = 0; kt < 32; ++kt) {
        int k0 = kt * 32;
        for (int i = 0; i < 2; ++i) {
            int row = srow + i * 64;
            const float* pa = Ag + (size_t)i * 64 * D_ + k0;
            float4_ a0 = *(const float4_*)(pa);
            float4_ a1 = *(const float4_*)(pa + 4);
            uint4_ va;
            va[0] = pack2(a0[0], a0[1]); va[1] = pack2(a0[2], a0[3]);
            va[2] = pack2(a1[0], a1[1]); va[3] = pack2(a1[2], a1[3]);
            uint4_ vb = *(const uint4_*)(Bg + (size_t)i * 64 * D_ + k0);
            *(uint4_*)(&As[row * 40 + skp]) = va;
            *(uint4_*)(&Bs[row * 40 + skp]) = vb;
        }
        __syncthreads();
        short8 af[4], bfr[4];
        for (int rt = 0; rt < 4; ++rt) af[rt]  = *(const short8*)(&As[(wr + rt * 16 + lrow) * 40 + lk8]);
        for (int ct = 0; ct < 4; ++ct) bfr[ct] = *(const short8*)(&Bs[(wc + ct * 16 + lrow) * 40 + lk8]);
        for (int rt = 0; rt < 4; ++rt)
            for (int ct = 0; ct < 4; ++ct)
                acc[rt][ct] = MFMA(af[rt], bfr[ct], acc[rt][ct]);
        __syncthreads();
    }

    int lrow4 = (lane >> 4) * 4, lcol = lane & 15;
    if (which < 2) {
        int lsh = (which == 0) ? 10 : 11;          // LQ=1024, LK=2048
        int Lm1 = (1 << lsh) - 1;
        unsigned short* dst = (which == 0) ? Qh : Kh;
        for (int rt = 0; rt < 4; ++rt)
            for (int ct = 0; ct < 4; ++ct)
                for (int i = 0; i < 4; ++i) {
                    int m = m0 + wr + rt * 16 + lrow4 + i;
                    int n = n0 + wc + ct * 16 + lcol;
                    float v = acc[rt][ct][i] + bias[n];
                    int b = m >> lsh, s = m & Lm1;
                    int h = n >> 6, d = n & 63;
                    dst[((size_t)((b * H_ + h) << lsh) + (size_t)s) * DH + d] = f2bf(v);
                }
    } else {
        for (int rt = 0; rt < 4; ++rt)
            for (int ct = 0; ct < 4; ++ct)
                for (int i = 0; i < 4; ++i) {
                    int rl = wr + rt * 16 + lrow4 + i;   // tile row (seq)
                    int cl = wc + ct * 16 + lcol;        // tile col (h*64+d)
                    float v = acc[rt][ct][i] + bias[n0 + cl];
                    Cs[cl * 136 + rl] = (short)f2bf(v);
                }
        __syncthreads();
        int b = m0 >> 11, r0 = m0 & 2047;
        int c = tid >> 1, half = tid & 1;
        int n = n0 + c, h = n >> 6, d = n & 63;
        unsigned short* dstp = VT + ((size_t)(b * H_ + h) * DH + d) * LK + r0 + half * 64;
        for (int j = 0; j < 8; ++j) {
            uint4_ v = *(const uint4_*)(&Cs[c * 136 + half * 64 + j * 8]);
            *(uint4_*)(dstp + j * 8) = v;
        }
    }
}

// ---------------------------------------------------------------------------
// Flash attention with relative_key_query pe terms.
// Round-8: round-4's proven L2-local config (bid mapping, 2 blocks/CU via
// 57.3KB LDS pad) + round-7's VALU wins (preconverted bf16 E, interleaved
// G2 b128 softmax gather) + register prefetch, now spill-free under
// __launch_bounds__(256,2) (VGPR budget 256).
// ---------------------------------------------------------------------------
__global__ __launch_bounds__(256, 2) void attn_kernel(
    const unsigned short* __restrict__ Qh, const unsigned short* __restrict__ Kh,
    const unsigned short* __restrict__ VT, const unsigned short* __restrict__ Eb,
    const float* __restrict__ mask, float* __restrict__ out)
{
    __shared__ short smem[28672];        // 57344 B: pads to force 2 blocks/CU
    short* Qs  = smem;                   // 64 x 72 (aliases Ks)
    short* Ks  = smem;                   // 64 x 72
    short* VTs = smem + 4608;            // 64 x 72 (d-major)
    short* Es  = smem + 9216;            // 128 x 72 (aliases G2)
    short* G2  = smem + 9216;            // 64 x 152

    int bid = blockIdx.x;
    int l0 = (bid & 15) * 64;            // round-4 mapping (proven L2-local)
    int bh = bid >> 4;
    int b  = bh >> 4, h = bh & 15;
    int tid = threadIdx.x, wave = tid >> 6, lane = tid & 63;
    int lr = lane & 15, lk8 = (lane >> 4) * 8, lr4 = (lane >> 4) * 4;

    // Stage Q tile, pull frags to registers; Qs memory is then released to Ks.
    for (int i = 0; i < 2; ++i) {
        int idx = tid + 256 * i, row = idx >> 3, g = (idx & 7) * 8;
        *(uint4_*)(&Qs[row * 72 + g]) =
            *(const uint4_*)(Qh + ((size_t)(bh * LQ + l0 + row)) * DH + g);
    }
    __syncthreads();
    short8 aq0 = *(const short8*)(&Qs[(wave * 16 + lr) * 72 + lk8]);
    short8 aq1 = *(const short8*)(&Qs[(wave * 16 + lr) * 72 + 32 + lk8]);

    float m_i[4], l_i[4];
    float4_ Oacc[4];
    for (int i = 0; i < 4; ++i) { m_i[i] = -1e30f; l_i[i] = 0.f; Oacc[i] = (float4_)0.f; }

    const unsigned short* Kbase = Kh + (size_t)bh * LK * DH;
    const unsigned short* Vbase = VT + (size_t)bh * DH * LK;

    int srow = tid >> 3;          // 0..31
    int sg   = (tid & 7) * 8;     // 0..56

    uint4_ kr0, kr1, vr0, vr1, er0, er1, er2, er3;
    auto load_tiles = [&](int it2) {
        int r0_ = it2 * 64, jb_ = l0 - r0_ + 1984;
        kr0 = *(const uint4_*)(Kbase + (size_t)(r0_ + srow) * DH + sg);
        kr1 = *(const uint4_*)(Kbase + (size_t)(r0_ + srow + 32) * DH + sg);
        vr0 = *(const uint4_*)(Vbase + (size_t)srow * LK + r0_ + sg);
        vr1 = *(const uint4_*)(Vbase + (size_t)(srow + 32) * LK + r0_ + sg);
        er0 = *(const uint4_*)(Eb + (size_t)(jb_ + srow) * DH + sg);
        er1 = *(const uint4_*)(Eb + (size_t)(jb_ + srow + 32) * DH + sg);
        er2 = *(const uint4_*)(Eb + (size_t)(jb_ + srow + 64) * DH + sg);
        er3 = *(const uint4_*)(Eb + (size_t)(jb_ + srow + 96) * DH + sg);
    };
    load_tiles(0);

    for (int it = 0; it < 32; ++it) {
        int r0 = it * 64;

        __syncthreads();   // (A) prior-iter readers done -> safe to restage
        *(uint4_*)(&Ks[srow * 72 + sg])         = kr0;
        *(uint4_*)(&Ks[(srow + 32) * 72 + sg])  = kr1;
        *(uint4_*)(&VTs[srow * 72 + sg])        = vr0;
        *(uint4_*)(&VTs[(srow + 32) * 72 + sg]) = vr1;
        *(uint4_*)(&Es[srow * 72 + sg])         = er0;
        *(uint4_*)(&Es[(srow + 32) * 72 + sg])  = er1;
        *(uint4_*)(&Es[(srow + 64) * 72 + sg])  = er2;
        *(uint4_*)(&Es[(srow + 96) * 72 + sg])  = er3;
        __syncthreads();   // (B) staging visible
        if (it < 31) load_tiles(it + 1);   // prefetch next tiles into regs

        // S = Q K^T
        float4_ Sacc[4];
        for (int c = 0; c < 4; ++c) {
            short8 b0 = *(const short8*)(&Ks[(c * 16 + lr) * 72 + lk8]);
            short8 b1 = *(const short8*)(&Ks[(c * 16 + lr) * 72 + 32 + lk8]);
            float4_ s = (float4_)0.f;
            s = MFMA(aq0, b0, s);
            s = MFMA(aq1, b1, s);
            Sacc[c] = s;
        }

        // Gq (u-tiles wave..wave+4), Gk (u-tiles 3-wave..7-wave); pack to bf16.
        short8 ak0 = *(const short8*)(&Ks[(wave * 16 + lr) * 72 + lk8]);
        short8 ak1 = *(const short8*)(&Ks[(wave * 16 + lr) * 72 + 32 + lk8]);
        unsigned int gqp[5][2], gkp[5][2];
        for (int tt = 0; tt < 5; ++tt) {
            int tqi = wave + tt;
            short8 e0 = *(const short8*)(&Es[(tqi * 16 + lr) * 72 + lk8]);
            short8 e1 = *(const short8*)(&Es[(tqi * 16 + lr) * 72 + 32 + lk8]);
            float4_ g = (float4_)0.f;
            g = MFMA(aq0, e0, g); g = MFMA(aq1, e1, g);
            gqp[tt][0] = pack2(g[0], g[1]); gqp[tt][1] = pack2(g[2], g[3]);
            int tk = (3 - wave) + tt;
            short8 f0 = *(const short8*)(&Es[(tk * 16 + lr) * 72 + lk8]);
            short8 f1 = *(const short8*)(&Es[(tk * 16 + lr) * 72 + 32 + lk8]);
            float4_ gg = (float4_)0.f;
            gg = MFMA(ak0, f0, gg); gg = MFMA(ak1, f1, gg);
            gkp[tt][0] = pack2(gg[0], gg[1]); gkp[tt][1] = pack2(gg[2], gg[3]);
        }
        __syncthreads();   // (C) all Es reads done -> scatter may overwrite union

        for (int tt = 0; tt < 5; ++tt) {
            int uq = (wave + tt) * 16 + lr;
            int uk = (3 - wave + tt) * 16 + lr;
            for (int i = 0; i < 4; ++i) {
                int row = wave * 16 + lr4 + i;
                unsigned int wq32 = gqp[tt][i >> 1], wk32 = gkp[tt][i >> 1];
                unsigned short vq = (unsigned short)((i & 1) ? (wq32 >> 16) : (wq32 & 0xffff));
                unsigned short vk = (unsigned short)((i & 1) ? (wk32 >> 16) : (wk32 & 0xffff));
                int tr = row - uq + 63;
                if ((unsigned)tr < 64u)
                    G2[row * 152 + (((tr & 15) ^ (row & 7)) << 3) + ((tr >> 4) << 1)] = (short)vq;
                int tl = uk + row - 63;
                if ((unsigned)tl < 64u)
                    G2[tl * 152 + (((row & 15) ^ (tl & 7)) << 3) + ((row >> 4) << 1) + 1] = (short)vk;
            }
        }
        __syncthreads();   // (D) scatter visible

        // Softmax rows + P write (row tl fully consumed before its P overwrite).
        float mk[4];
        for (int c = 0; c < 4; ++c) mk[c] = mask[b * LK + r0 + c * 16 + lr];
        for (int i = 0; i < 4; ++i) {
            int tl = wave * 16 + lr4 + i;
            short8 gv = *(const short8*)(&G2[tl * 152 + ((lr ^ (tl & 7)) << 3)]);
            float scv[4], mx = -1e30f;
            for (int c = 0; c < 4; ++c) {
                float sq = bf2f((unsigned short)gv[2 * c]);
                float sk = bf2f((unsigned short)gv[2 * c + 1]);
                float sc = (Sacc[c][i] + sq + sk) * 0.125f + mk[c];
                scv[c] = sc;
                mx = fmaxf(mx, sc);
            }
            for (int off = 1; off < 16; off <<= 1) mx = fmaxf(mx, __shfl_xor(mx, off, 64));
            float mnew = fmaxf(m_i[i], mx);
            float alpha = __expf(m_i[i] - mnew);
            m_i[i] = mnew;
            float e0 = __expf(scv[0] - mnew), e1 = __expf(scv[1] - mnew);
            float e2 = __expf(scv[2] - mnew), e3 = __expf(scv[3] - mnew);
            unsigned int p01 = pack2(e0, e1), p23 = pack2(e2, e3);
            float rs = bf2f((unsigned short)(p01 & 0xffff)) + bf2f((unsigned short)(p01 >> 16))
                     + bf2f((unsigned short)(p23 & 0xffff)) + bf2f((unsigned short)(p23 >> 16));
            for (int off = 1; off < 16; off <<= 1) rs += __shfl_xor(rs, off, 64);
            l_i[i] = l_i[i] * alpha + rs;
            for (int nt = 0; nt < 4; ++nt) Oacc[nt][i] *= alpha;
            G2[tl * 152 +  0 + lr] = (short)(unsigned short)(p01 & 0xffff);
            G2[tl * 152 + 16 + lr] = (short)(unsigned short)(p01 >> 16);
            G2[tl * 152 + 32 + lr] = (short)(unsigned short)(p23 & 0xffff);
            G2[tl * 152 + 48 + lr] = (short)(unsigned short)(p23 >> 16);
        }
        // P·V (P A-frags from G2 rows; same-wave in-order LDS => safe)
        short8 ap0 = *(const short8*)(&G2[(wave * 16 + lr) * 152 + lk8]);
        short8 ap1 = *(const short8*)(&G2[(wave * 16 + lr) * 152 + 32 + lk8]);
        for (int nt = 0; nt < 4; ++nt) {
            short8 v0 = *(const short8*)(&VTs[(nt * 16 + lr) * 72 + lk8]);
            short8 v1 = *(const short8*)(&VTs[(nt * 16 + lr) * 72 + 32 + lk8]);
            Oacc[nt] = MFMA(ap0, v0, Oacc[nt]);
            Oacc[nt] = MFMA(ap1, v1, Oacc[nt]);
        }
    }

    // Epilogue: out[b][l][h*64+d] = O / l_i   (fp32 output)
    for (int nt = 0; nt < 4; ++nt)
        for (int i = 0; i < 4; ++i) {
            int row = l0 + wave * 16 + lr4 + i;
            int col = h * 64 + nt * 16 + lr;
            out[(size_t)(b * LQ + row) * D_ + col] = Oacc[nt][i] / l_i[i];
        }
}

extern "C" void kernel_launch(void* const* d_in, const int* in_sizes, int n_in,
                              void* d_out, int out_size, void* d_ws, size_t ws_size,
                              hipStream_t stream) {
    (void)in_sizes; (void)n_in; (void)out_size; (void)ws_size;
    const float* Xk   = (const float*)d_in[0]; // hidden_states [4,2048,1024] fp32
    const float* Xq   = (const float*)d_in[1]; // query_hidden  [4,1024,1024] fp32
    const float* mask = (const float*)d_in[2]; // [4,1,1,2048] fp32
    const float* Wq   = (const float*)d_in[3];
    const float* bq   = (const float*)d_in[4];
    const float* Wk   = (const float*)d_in[5];
    const float* bk   = (const float*)d_in[6];
    const float* Wv   = (const float*)d_in[7];
    const float* bv   = (const float*)d_in[8];
    const float* Eg   = (const float*)d_in[9]; // dist_emb [4095,64] fp32

    // workspace layout (bf16 elems), total ~48.8 MB
    unsigned short* Qh  = (unsigned short*)d_ws;              //  4,194,304
    unsigned short* Kh  = Qh  + (size_t)4194304;              //  8,388,608
    unsigned short* VT  = Kh  + (size_t)8388608;              //  8,388,608
    unsigned short* cWq = VT  + (size_t)8388608;              //  1,048,576
    unsigned short* cWk = cWq + (size_t)1048576;              //  1,048,576
    unsigned short* cWv = cWk + (size_t)1048576;              //  1,048,576
    unsigned short* cEb = cWv + (size_t)1048576;              //    262,144 (pad)
    float* o = (float*)d_out;

    conv_kernel<<<1664, 256, 0, stream>>>(Wq, Wk, Wv, Eg, cWq, cWk, cWv, cEb);
    proj_kernel<<<1280, 256, 0, stream>>>(Xq, Xk, cWq, bq, cWk, bk, cWv, bv, Qh, Kh, VT);
    attn_kernel<<<1024, 256, 0, stream>>>(Qh, Kh, VT, cEb, mask, o);
}

// Round 9
// 489.899 us; speedup vs baseline: 2.0370x; 1.0925x over previous
//
#include <hip/hip_runtime.h>
#include <hip/hip_bf16.h>

#define B_   4
#define H_   16
#define LQ   1024
#define LK   2048
#define D_   1024
#define DH   64

typedef __attribute__((ext_vector_type(8))) short  short8;
typedef __attribute__((ext_vector_type(4))) float  float4_;
typedef __attribute__((ext_vector_type(4))) unsigned int uint4_;

static __device__ __forceinline__ float bf2f(unsigned short u) {
    unsigned int x = ((unsigned int)u) << 16;
    return __builtin_bit_cast(float, x);
}
static __device__ __forceinline__ unsigned short f2bf(float f) {
    unsigned int x = __builtin_bit_cast(unsigned int, f);
    unsigned int lsb = (x >> 16) & 1u;
    x += 0x7fffu + lsb;
    return (unsigned short)(x >> 16);
}
// packed RNE fp32x2 -> bf16x2 (v_cvt_pk_bf16_f32 on gfx950)
static __device__ __forceinline__ unsigned int pack2(float a, float b) {
    __hip_bfloat162 h = __float22bfloat162_rn(make_float2(a, b));
    unsigned int r;
    __builtin_memcpy(&r, &h, 4);
    return r;
}

#define MFMA(a, b, c) __builtin_amdgcn_mfma_f32_16x16x32_bf16((a), (b), (c), 0, 0, 0)

// G2 row base: stride 144 shorts + 8 extra every 4 rows.
// -> 4-row lane-groups sit 292 dwords apart == 4 mod 32: distinct bank quads.
#define G2ROW(tl) ((tl) * 144 + ((tl) >> 2) * 8)

// ---------------------------------------------------------------------------
// One-shot fp32 -> bf16 conversion: Wq, Wk, Wv (1M elems each), dist_emb.
// ---------------------------------------------------------------------------
__global__ __launch_bounds__(256) void conv_kernel(
    const float* __restrict__ Wq, const float* __restrict__ Wk,
    const float* __restrict__ Wv, const float* __restrict__ Eg,
    unsigned short* __restrict__ cWq, unsigned short* __restrict__ cWk,
    unsigned short* __restrict__ cWv, unsigned short* __restrict__ cEb)
{
    int bid = blockIdx.x;
    const float* src; unsigned short* dst; int nch;
    if (bid < 512)       { src = Wq; dst = cWq;              nch = 131072; }
    else if (bid < 1024) { src = Wk; dst = cWk; bid -= 512;  nch = 131072; }
    else if (bid < 1536) { src = Wv; dst = cWv; bid -= 1024; nch = 131072; }
    else                 { src = Eg; dst = cEb; bid -= 1536; nch = 32760;  }
    int ch = bid * 256 + threadIdx.x;
    if (ch >= nch) return;
    const float* s = src + (size_t)ch * 8;
    float4_ v0 = *(const float4_*)s, v1 = *(const float4_*)(s + 4);
    uint4_ o;
    o[0] = pack2(v0[0], v0[1]); o[1] = pack2(v0[2], v0[3]);
    o[2] = pack2(v1[0], v1[1]); o[3] = pack2(v1[2], v1[3]);
    *(uint4_*)(dst + (size_t)ch * 8) = o;
}

// ---------------------------------------------------------------------------
// Projection GEMM: X fp32 (packed in staging), W bf16 (preconverted).
// which 0: Q -> Qh ; 1: K -> Kh ; 2: V -> VT (transposed via LDS).
// ---------------------------------------------------------------------------
__global__ __launch_bounds__(256) void proj_kernel(
    const float* __restrict__ Xq, const float* __restrict__ Xk,
    const unsigned short* __restrict__ Wq, const float* __restrict__ bq,
    const unsigned short* __restrict__ Wk, const float* __restrict__ bk,
    const unsigned short* __restrict__ Wv, const float* __restrict__ bv,
    unsigned short* __restrict__ Qh, unsigned short* __restrict__ Kh,
    unsigned short* __restrict__ VT)
{
    __shared__ short smem[17408];
    short* As = smem;                  // 128 x 40 bf16
    short* Bs = smem + 5120;           // 128 x 40 bf16
    short* Cs = smem;                  // 128 x 136 (V transpose, aliases)

    int bid = blockIdx.x;
    int which, tm, tn;
    const float *X, *bias; const unsigned short* W;
    if (bid < 256)      { which = 0; int t = bid;       tm = t >> 3; tn = t & 7; X = Xq; W = Wq; bias = bq; }
    else if (bid < 768) { which = 1; int t = bid - 256; tm = t >> 3; tn = t & 7; X = Xk; W = Wk; bias = bk; }
    else                { which = 2; int t = bid - 768; tm = t >> 3; tn = t & 7; X = Xk; W = Wv; bias = bv; }

    int tid  = threadIdx.x;
    int wave = tid >> 6, lane = tid & 63;
    int wr = (wave >> 1) * 64, wc = (wave & 1) * 64;
    int m0 = tm * 128, n0 = tn * 128;

    float4_ acc[4][4];
    for (int a = 0; a < 4; ++a) for (int c = 0; c < 4; ++c) acc[a][c] = (float4_)0.0f;

    int srow = tid >> 2, skp = (tid & 3) * 8;
    const float*          Ag = X + (size_t)(m0 + srow) * D_ + skp;
    const unsigned short* Bg = W + (size_t)(n0 + srow) * D_ + skp;
    int lrow = lane & 15, lk8 = (lane >> 4) * 8;

    for (int kt = 0; kt < 32; ++kt) {
        int k0 = kt * 32;
        for (int i = 0; i < 2; ++i) {
            int row = srow + i * 64;
            const float* pa = Ag + (size_t)i * 64 * D_ + k0;
            float4_ a0 = *(const float4_*)(pa);
            float4_ a1 = *(const float4_*)(pa + 4);
            uint4_ va;
            va[0] = pack2(a0[0], a0[1]); va[1] = pack2(a0[2], a0[3]);
            va[2] = pack2(a1[0], a1[1]); va[3] = pack2(a1[2], a1[3]);
            uint4_ vb = *(const uint4_*)(Bg + (size_t)i * 64 * D_ + k0);
            *(uint4_*)(&As[row * 40 + skp]) = va;
            *(uint4_*)(&Bs[row * 40 + skp]) = vb;
        }
        __syncthreads();
        short8 af[4], bfr[4];
        for (int rt = 0; rt < 4; ++rt) af[rt]  = *(const short8*)(&As[(wr + rt * 16 + lrow) * 40 + lk8]);
        for (int ct = 0; ct < 4; ++ct) bfr[ct] = *(const short8*)(&Bs[(wc + ct * 16 + lrow) * 40 + lk8]);
        for (int rt = 0; rt < 4; ++rt)
            for (int ct = 0; ct < 4; ++ct)
                acc[rt][ct] = MFMA(af[rt], bfr[ct], acc[rt][ct]);
        __syncthreads();
    }

    int lrow4 = (lane >> 4) * 4, lcol = lane & 15;
    if (which < 2) {
        int lsh = (which == 0) ? 10 : 11;          // LQ=1024, LK=2048
        int Lm1 = (1 << lsh) - 1;
        unsigned short* dst = (which == 0) ? Qh : Kh;
        for (int rt = 0; rt < 4; ++rt)
            for (int ct = 0; ct < 4; ++ct)
                for (int i = 0; i < 4; ++i) {
                    int m = m0 + wr + rt * 16 + lrow4 + i;
                    int n = n0 + wc + ct * 16 + lcol;
                    float v = acc[rt][ct][i] + bias[n];
                    int b = m >> lsh, s = m & Lm1;
                    int h = n >> 6, d = n & 63;
                    dst[((size_t)((b * H_ + h) << lsh) + (size_t)s) * DH + d] = f2bf(v);
                }
    } else {
        for (int rt = 0; rt < 4; ++rt)
            for (int ct = 0; ct < 4; ++ct)
                for (int i = 0; i < 4; ++i) {
                    int rl = wr + rt * 16 + lrow4 + i;   // tile row (seq)
                    int cl = wc + ct * 16 + lcol;        // tile col (h*64+d)
                    float v = acc[rt][ct][i] + bias[n0 + cl];
                    Cs[cl * 136 + rl] = (short)f2bf(v);
                }
        __syncthreads();
        int b = m0 >> 11, r0 = m0 & 2047;
        int c = tid >> 1, half = tid & 1;
        int n = n0 + c, h = n >> 6, d = n & 63;
        unsigned short* dstp = VT + ((size_t)(b * H_ + h) * DH + d) * LK + r0 + half * 64;
        for (int j = 0; j < 8; ++j) {
            uint4_ v = *(const uint4_*)(&Cs[c * 136 + half * 64 + j * 8]);
            *(uint4_*)(dstp + j * 8) = v;
        }
    }
}

// ---------------------------------------------------------------------------
// Flash attention with relative_key_query pe terms.
// Round-9: bank-exact G2 (G2ROW stride, no XOR; both Gq and Gk stored at
// row tl so one b128 gather/row serves softmax), Es de-aliased from G2
// (drops one barrier -> 3/iter), register prefetch kept, 2 blocks/CU kept.
// ---------------------------------------------------------------------------
__global__ __launch_bounds__(256, 2) void attn_kernel(
    const unsigned short* __restrict__ Qh, const unsigned short* __restrict__ Kh,
    const unsigned short* __restrict__ VT, const unsigned short* __restrict__ Eb,
    const float* __restrict__ mask, float* __restrict__ out)
{
    __shared__ short smem[27776];        // 55552 B -> 2 blocks/CU
    short* Qs  = smem;                   // 64 x 72 (aliases Ks)
    short* Ks  = smem;                   // 64 x 72
    short* VTs = smem + 4608;            // 64 x 72 (d-major)
    short* Es  = smem + 9216;            // 128 x 72
    short* G2  = smem + 18432;           // G2ROW layout, 9344 shorts
    short* Ps  = G2;                     // P overwrites G2 rows after gather

    int bid = blockIdx.x;
    int l0 = (bid & 15) * 64;            // L2-local mapping (r4-proven)
    int bh = bid >> 4;
    int b  = bh >> 4, h = bh & 15;
    int tid = threadIdx.x, wave = tid >> 6, lane = tid & 63;
    int lr = lane & 15, lk8 = (lane >> 4) * 8, lr4 = (lane >> 4) * 4;

    // Stage Q tile, pull frags to registers; Qs memory is then released to Ks.
    for (int i = 0; i < 2; ++i) {
        int idx = tid + 256 * i, row = idx >> 3, g = (idx & 7) * 8;
        *(uint4_*)(&Qs[row * 72 + g]) =
            *(const uint4_*)(Qh + ((size_t)(bh * LQ + l0 + row)) * DH + g);
    }
    __syncthreads();
    short8 aq0 = *(const short8*)(&Qs[(wave * 16 + lr) * 72 + lk8]);
    short8 aq1 = *(const short8*)(&Qs[(wave * 16 + lr) * 72 + 32 + lk8]);

    float m_i[4], l_i[4];
    float4_ Oacc[4];
    for (int i = 0; i < 4; ++i) { m_i[i] = -1e30f; l_i[i] = 0.f; Oacc[i] = (float4_)0.f; }

    const unsigned short* Kbase = Kh + (size_t)bh * LK * DH;
    const unsigned short* Vbase = VT + (size_t)bh * DH * LK;

    int srow = tid >> 3;          // 0..31
    int sg   = (tid & 7) * 8;     // 0..56

    uint4_ kr0, kr1, vr0, vr1, er0, er1, er2, er3;
    auto load_tiles = [&](int it2) {
        int r0_ = it2 * 64, jb_ = l0 - r0_ + 1984;
        kr0 = *(const uint4_*)(Kbase + (size_t)(r0_ + srow) * DH + sg);
        kr1 = *(const uint4_*)(Kbase + (size_t)(r0_ + srow + 32) * DH + sg);
        vr0 = *(const uint4_*)(Vbase + (size_t)srow * LK + r0_ + sg);
        vr1 = *(const uint4_*)(Vbase + (size_t)(srow + 32) * LK + r0_ + sg);
        er0 = *(const uint4_*)(Eb + (size_t)(jb_ + srow) * DH + sg);
        er1 = *(const uint4_*)(Eb + (size_t)(jb_ + srow + 32) * DH + sg);
        er2 = *(const uint4_*)(Eb + (size_t)(jb_ + srow + 64) * DH + sg);
        er3 = *(const uint4_*)(Eb + (size_t)(jb_ + srow + 96) * DH + sg);
    };
    load_tiles(0);

    for (int it = 0; it < 32; ++it) {
        int r0 = it * 64;

        __syncthreads();   // (A) prior-iter readers done -> safe to restage
        *(uint4_*)(&Ks[srow * 72 + sg])         = kr0;
        *(uint4_*)(&Ks[(srow + 32) * 72 + sg])  = kr1;
        *(uint4_*)(&VTs[srow * 72 + sg])        = vr0;
        *(uint4_*)(&VTs[(srow + 32) * 72 + sg]) = vr1;
        *(uint4_*)(&Es[srow * 72 + sg])         = er0;
        *(uint4_*)(&Es[(srow + 32) * 72 + sg])  = er1;
        *(uint4_*)(&Es[(srow + 64) * 72 + sg])  = er2;
        *(uint4_*)(&Es[(srow + 96) * 72 + sg])  = er3;
        __syncthreads();   // (B) staging visible
        if (it < 31) load_tiles(it + 1);   // prefetch next tiles into regs

        // S = Q K^T
        float4_ Sacc[4];
        for (int c = 0; c < 4; ++c) {
            short8 b0 = *(const short8*)(&Ks[(c * 16 + lr) * 72 + lk8]);
            short8 b1 = *(const short8*)(&Ks[(c * 16 + lr) * 72 + 32 + lk8]);
            float4_ s = (float4_)0.f;
            s = MFMA(aq0, b0, s);
            s = MFMA(aq1, b1, s);
            Sacc[c] = s;
        }

        // Gq (u-tiles wave..wave+4), Gk (u-tiles 3-wave..7-wave); pack bf16.
        short8 ak0 = *(const short8*)(&Ks[(wave * 16 + lr) * 72 + lk8]);
        short8 ak1 = *(const short8*)(&Ks[(wave * 16 + lr) * 72 + 32 + lk8]);
        unsigned int gqp[5][2], gkp[5][2];
        for (int tt = 0; tt < 5; ++tt) {
            int tqi = wave + tt;
            short8 e0 = *(const short8*)(&Es[(tqi * 16 + lr) * 72 + lk8]);
            short8 e1 = *(const short8*)(&Es[(tqi * 16 + lr) * 72 + 32 + lk8]);
            float4_ g = (float4_)0.f;
            g = MFMA(aq0, e0, g); g = MFMA(aq1, e1, g);
            gqp[tt][0] = pack2(g[0], g[1]); gqp[tt][1] = pack2(g[2], g[3]);
            int tk = (3 - wave) + tt;
            short8 f0 = *(const short8*)(&Es[(tk * 16 + lr) * 72 + lk8]);
            short8 f1 = *(const short8*)(&Es[(tk * 16 + lr) * 72 + 32 + lk8]);
            float4_ gg = (float4_)0.f;
            gg = MFMA(ak0, f0, gg); gg = MFMA(ak1, f1, gg);
            gkp[tt][0] = pack2(gg[0], gg[1]); gkp[tt][1] = pack2(gg[2], gg[3]);
        }

        // Scatter into G2 rows (row = tl for BOTH q and k terms).
        // slot(tl,tr,qk) = G2ROW(tl) + (tr&15)*8 + (tr>>4)*2 + qk
        for (int tt = 0; tt < 5; ++tt) {
            int uq = (wave + tt) * 16 + lr;
            int uk = (3 - wave + tt) * 16 + lr;
            for (int i = 0; i < 4; ++i) {
                int row = wave * 16 + lr4 + i;           // Q-row for Gq, K-row for Gk
                unsigned int wq32 = gqp[tt][i >> 1], wk32 = gkp[tt][i >> 1];
                unsigned short vq = (unsigned short)((i & 1) ? (wq32 >> 16) : (wq32 & 0xffff));
                unsigned short vk = (unsigned short)((i & 1) ? (wk32 >> 16) : (wk32 & 0xffff));
                int tr = row - uq + 63;                  // Gq col
                if ((unsigned)tr < 64u)
                    G2[G2ROW(row) + ((tr & 15) << 3) + (((tr >> 4)) << 1)] = (short)vq;
                int tl = uk + row - 63;                  // Gk row (col = row)
                if ((unsigned)tl < 64u)
                    G2[G2ROW(tl) + ((row & 15) << 3) + (((row >> 4)) << 1) + 1] = (short)vk;
            }
        }
        __syncthreads();   // (D) scatter visible

        // Softmax rows + P write (row tl fully consumed before its P overwrite;
        // gather/ap touch only own-wave rows -> same-wave in-order safe).
        float mk[4];
        for (int c = 0; c < 4; ++c) mk[c] = mask[b * LK + r0 + c * 16 + lr];
        for (int i = 0; i < 4; ++i) {
            int tl = wave * 16 + lr4 + i;
            short8 gv = *(const short8*)(&G2[G2ROW(tl) + (lr << 3)]);
            float scv[4], mx = -1e30f;
            for (int c = 0; c < 4; ++c) {
                float sq = bf2f((unsigned short)gv[2 * c]);
                float sk = bf2f((unsigned short)gv[2 * c + 1]);
                float sc = (Sacc[c][i] + sq + sk) * 0.125f + mk[c];
                scv[c] = sc;
                mx = fmaxf(mx, sc);
            }
            for (int off = 1; off < 16; off <<= 1) mx = fmaxf(mx, __shfl_xor(mx, off, 64));
            float mnew = fmaxf(m_i[i], mx);
            float alpha = __expf(m_i[i] - mnew);
            m_i[i] = mnew;
            float e0 = __expf(scv[0] - mnew), e1 = __expf(scv[1] - mnew);
            float e2 = __expf(scv[2] - mnew), e3 = __expf(scv[3] - mnew);
            unsigned int p01 = pack2(e0, e1), p23 = pack2(e2, e3);
            float rs = bf2f((unsigned short)(p01 & 0xffff)) + bf2f((unsigned short)(p01 >> 16))
                     + bf2f((unsigned short)(p23 & 0xffff)) + bf2f((unsigned short)(p23 >> 16));
            for (int off = 1; off < 16; off <<= 1) rs += __shfl_xor(rs, off, 64);
            l_i[i] = l_i[i] * alpha + rs;
            for (int nt = 0; nt < 4; ++nt) Oacc[nt][i] *= alpha;
            Ps[G2ROW(tl) +  0 + lr] = (short)(unsigned short)(p01 & 0xffff);
            Ps[G2ROW(tl) + 16 + lr] = (short)(unsigned short)(p01 >> 16);
            Ps[G2ROW(tl) + 32 + lr] = (short)(unsigned short)(p23 & 0xffff);
            Ps[G2ROW(tl) + 48 + lr] = (short)(unsigned short)(p23 >> 16);
        }
        // P·V (P A-frags from G2 rows, row-major within row; same-wave safe)
        short8 ap0 = *(const short8*)(&Ps[G2ROW(wave * 16 + lr) + lk8]);
        short8 ap1 = *(const short8*)(&Ps[G2ROW(wave * 16 + lr) + 32 + lk8]);
        for (int nt = 0; nt < 4; ++nt) {
            short8 v0 = *(const short8*)(&VTs[(nt * 16 + lr) * 72 + lk8]);
            short8 v1 = *(const short8*)(&VTs[(nt * 16 + lr) * 72 + 32 + lk8]);
            Oacc[nt] = MFMA(ap0, v0, Oacc[nt]);
            Oacc[nt] = MFMA(ap1, v1, Oacc[nt]);
        }
    }

    // Epilogue: out[b][l][h*64+d] = O / l_i   (fp32 output)
    for (int nt = 0; nt < 4; ++nt)
        for (int i = 0; i < 4; ++i) {
            int row = l0 + wave * 16 + lr4 + i;
            int col = h * 64 + nt * 16 + lr;
            out[(size_t)(b * LQ + row) * D_ + col] = Oacc[nt][i] / l_i[i];
        }
}

extern "C" void kernel_launch(void* const* d_in, const int* in_sizes, int n_in,
                              void* d_out, int out_size, void* d_ws, size_t ws_size,
                              hipStream_t stream) {
    (void)in_sizes; (void)n_in; (void)out_size; (void)ws_size;
    const float* Xk   = (const float*)d_in[0]; // hidden_states [4,2048,1024] fp32
    const float* Xq   = (const float*)d_in[1]; // query_hidden  [4,1024,1024] fp32
    const float* mask = (const float*)d_in[2]; // [4,1,1,2048] fp32
    const float* Wq   = (const float*)d_in[3];
    const float* bq   = (const float*)d_in[4];
    const float* Wk   = (const float*)d_in[5];
    const float* bk   = (const float*)d_in[6];
    const float* Wv   = (const float*)d_in[7];
    const float* bv   = (const float*)d_in[8];
    const float* Eg   = (const float*)d_in[9]; // dist_emb [4095,64] fp32

    // workspace layout (bf16 elems), total ~48.8 MB
    unsigned short* Qh  = (unsigned short*)d_ws;              //  4,194,304
    unsigned short* Kh  = Qh  + (size_t)4194304;              //  8,388,608
    unsigned short* VT  = Kh  + (size_t)8388608;              //  8,388,608
    unsigned short* cWq = VT  + (size_t)8388608;              //  1,048,576
    unsigned short* cWk = cWq + (size_t)1048576;              //  1,048,576
    unsigned short* cWv = cWk + (size_t)1048576;              //  1,048,576
    unsigned short* cEb = cWv + (size_t)1048576;              //    262,144 (pad)
    float* o = (float*)d_out;

    conv_kernel<<<1664, 256, 0, stream>>>(Wq, Wk, Wv, Eg, cWq, cWk, cWv, cEb);
    proj_kernel<<<1280, 256, 0, stream>>>(Xq, Xk, cWq, bq, cWk, bk, cWv, bv, Qh, Kh, VT);
    attn_kernel<<<1024, 256, 0, stream>>>(Qh, Kh, VT, cEb, mask, o);
}